// Round 1
// baseline (786.126 us; speedup 1.0000x reference)
//
#include <hip/hip_runtime.h>
#include <math.h>

#define TOK   8192
#define DD    1024
#define EE    8
#define HH    4096
#define MAXROWS 9216   // 8192 + 8*128 headroom, = 72 tiles * 128
#define MAXMT 72

typedef unsigned short u16;
typedef unsigned int   u32;
typedef __bf16 bf16x8 __attribute__((ext_vector_type(8)));
typedef float  f32x4  __attribute__((ext_vector_type(4)));

__device__ __forceinline__ u16 f2bf(float f) {
  union { float f; u32 u; } v; v.f = f;
  u32 r = v.u + 0x7fffu + ((v.u >> 16) & 1u);   // RNE, finite inputs only
  return (u16)(r >> 16);
}

__device__ __forceinline__ void gload16(const void* g, void* l) {
  __builtin_amdgcn_global_load_lds(
      (const __attribute__((address_space(1))) void*)g,
      (__attribute__((address_space(3))) void*)l, 16, 0, 0);
}

// ---------------- init: rowmap=-1, zero atomic counters ----------------
__global__ void k_init(int* rowmap, int* counts, int* fill) {
  int i = blockIdx.x * 256 + threadIdx.x;
  if (i < MAXROWS) rowmap[i] = -1;
  if (blockIdx.x == 0 && threadIdx.x < EE) { counts[threadIdx.x] = 0; fill[threadIdx.x] = 0; }
}

// ---------------- routing: argmax of x@Wr + br (softmax is monotone) ----------------
__global__ __launch_bounds__(256)
void k_route(const float* __restrict__ x, const float* __restrict__ Wr,
             const float* __restrict__ br, int* __restrict__ eid, int* __restrict__ counts) {
  int t = blockIdx.x;
  const float* xr = x + (size_t)t * DD;
  float acc[EE];
  #pragma unroll
  for (int e = 0; e < EE; ++e) acc[e] = 0.f;
  for (int d = threadIdx.x; d < DD; d += 256) {
    float xv = xr[d];
    const float4* wrow = (const float4*)(Wr + (size_t)d * EE);
    float4 a = wrow[0], b = wrow[1];
    acc[0] += xv * a.x; acc[1] += xv * a.y; acc[2] += xv * a.z; acc[3] += xv * a.w;
    acc[4] += xv * b.x; acc[5] += xv * b.y; acc[6] += xv * b.z; acc[7] += xv * b.w;
  }
  #pragma unroll
  for (int e = 0; e < EE; ++e)
    for (int off = 32; off > 0; off >>= 1) acc[e] += __shfl_down(acc[e], off);
  __shared__ float red[4][EE];
  int w = threadIdx.x >> 6, lt = threadIdx.x & 63;
  if (lt == 0) {
    #pragma unroll
    for (int e = 0; e < EE; ++e) red[w][e] = acc[e];
  }
  __syncthreads();
  if (threadIdx.x == 0) {
    float best = -1e30f; int be = 0;
    #pragma unroll
    for (int e = 0; e < EE; ++e) {
      float v = red[0][e] + red[1][e] + red[2][e] + red[3][e] + br[e];
      if (v > best) { best = v; be = e; }   // strict > keeps first index on tie (jnp.argmax)
    }
    eid[t] = be;
    atomicAdd(&counts[be], 1);
  }
}

// ---------------- scan: padded (×128) segment offsets ----------------
__global__ void k_scan(const int* __restrict__ counts, int* __restrict__ poff) {
  if (threadIdx.x == 0) {
    int off = 0; poff[0] = 0;
    for (int e = 0; e < EE; ++e) { off += ((counts[e] + 127) >> 7) << 7; poff[e + 1] = off; }
  }
}

// ---------------- fill rowmap: padded row -> token ----------------
__global__ void k_fillmap(const int* __restrict__ eid, const int* __restrict__ poff,
                          int* __restrict__ fill, int* __restrict__ rowmap) {
  int t = blockIdx.x * 256 + threadIdx.x;
  if (t < TOK) {
    int e = eid[t];
    int pos = atomicAdd(&fill[e], 1);
    rowmap[poff[e] + pos] = t;
  }
}

// ---------------- x fp32 -> bf16 ----------------
__global__ void k_convx(const float* __restrict__ x, u16* __restrict__ xb) {
  int i = blockIdx.x * 256 + threadIdx.x;   // one float4 per thread, exact grid
  float4 v = ((const float4*)x)[i];
  u32 p0 = (u32)f2bf(v.x) | ((u32)f2bf(v.y) << 16);
  u32 p1 = (u32)f2bf(v.z) | ((u32)f2bf(v.w) << 16);
  ((uint2*)xb)[i] = make_uint2(p0, p1);
}

// ---------------- W [E][K][N] fp32 -> WT [E][N][K] bf16 (K-contiguous) ----------------
__global__ __launch_bounds__(256)
void k_transpose(const float* __restrict__ W, u16* __restrict__ WT, int K, int N) {
  __shared__ float tile[32][33];
  int e = blockIdx.z;
  int n0 = blockIdx.x * 32, k0 = blockIdx.y * 32;
  const float* We = W + (size_t)e * K * N;
  u16* WTe = WT + (size_t)e * K * N;
  int tx = threadIdx.x & 31, ty = threadIdx.x >> 5;
  #pragma unroll
  for (int i = 0; i < 4; ++i)
    tile[ty + 8 * i][tx] = We[(size_t)(k0 + ty + 8 * i) * N + n0 + tx];
  __syncthreads();
  #pragma unroll
  for (int i = 0; i < 4; ++i)
    WTe[(size_t)(n0 + ty + 8 * i) * K + k0 + tx] = f2bf(tile[tx][ty + 8 * i]);
}

// ---------------- 128x128 bf16 MFMA GEMM, BK=64, XOR-swizzled LDS ----------------
// G2=false: C = gather(xbf) @ W1T[e]^T, epilogue bias+gelu -> h (bf16)
// G2=true : C = h @ W2T[e]^T, epilogue bias -> scatter fp32 to out
template <int KDIM, int NDIM, bool G2>
__global__ __launch_bounds__(256)
void k_gemm(const u16* __restrict__ Abase, const u16* __restrict__ WT,
            const float* __restrict__ bias, const int* __restrict__ poff,
            const int* __restrict__ rowmap, u16* __restrict__ hout,
            float* __restrict__ yout) {
  const int mt = blockIdx.y;
  const int mlimit = poff[EE];
  const int mbase = mt * 128;
  if (mbase >= mlimit) return;
  int e = 0;
  #pragma unroll
  for (int q = 1; q < EE; ++q) e += (mbase >= poff[q]) ? 1 : 0;

  const int nbase = blockIdx.x * 128;
  const int tid = threadIdx.x;
  const int w = tid >> 6;         // wave 0..3 (2x2)
  const int lt = tid & 63;
  const int wr = w >> 1, wc = w & 1;

  __shared__ u16 lsA[128 * 64];   // [row][k] chunks XOR-swizzled: phys = row*8 + (c ^ (row&7))
  __shared__ u16 lsB[128 * 64];

  // staging: lane -> (row = w*32+q*8 + lt/8, logical chunk c = (lt%8) ^ (row&7))
  const int lrow = lt >> 3, lcol = lt & 7;
  const int cwz = lcol ^ lrow;    // since row&7 == lrow for q*8-aligned bases

  const u16* wte = WT + (size_t)e * NDIM * KDIM;
  const u16* gA[4]; const u16* gB[4];
  #pragma unroll
  for (int q = 0; q < 4; ++q) {
    int rq = w * 32 + q * 8 + lrow;
    int arow;
    if (G2) { arow = mbase + rq; }
    else { arow = rowmap[mbase + rq]; if (arow < 0) arow = 0; }  // pad rows read token 0; garbage discarded
    gA[q] = Abase + (size_t)arow * KDIM + cwz * 8;
    gB[q] = wte + (size_t)(nbase + rq) * KDIM + cwz * 8;
  }

  f32x4 acc[4][4] = {};

  const int KT = KDIM / 64;
  for (int bk = 0; bk < KT; ++bk) {
    __syncthreads();   // prior iter's ds_reads complete before overwrite
    #pragma unroll
    for (int q = 0; q < 4; ++q) {
      gload16(gA[q] + bk * 64, &lsA[(w * 32 + q * 8) * 64]);
      gload16(gB[q] + bk * 64, &lsB[(w * 32 + q * 8) * 64]);
    }
    __syncthreads();   // compiler drains vmcnt before s_barrier
    #pragma unroll
    for (int s = 0; s < 2; ++s) {
      const int quad = lt >> 4;
      const int cc = s * 4 + quad;
      bf16x8 af[4], bfv[4];
      #pragma unroll
      for (int i = 0; i < 4; ++i) {
        int row = wr * 64 + i * 16 + (lt & 15);
        int phys = row * 8 + (cc ^ (row & 7));
        af[i] = *(const bf16x8*)&lsA[phys * 8];
      }
      #pragma unroll
      for (int j = 0; j < 4; ++j) {
        int n = wc * 64 + j * 16 + (lt & 15);
        int phys = n * 8 + (cc ^ (n & 7));
        bfv[j] = *(const bf16x8*)&lsB[phys * 8];
      }
      #pragma unroll
      for (int i = 0; i < 4; ++i)
        #pragma unroll
        for (int j = 0; j < 4; ++j)
          acc[i][j] = __builtin_amdgcn_mfma_f32_16x16x32_bf16(af[i], bfv[j], acc[i][j], 0, 0, 0);
    }
  }

  // epilogue. C/D layout: col = lt&15, row = (lt>>4)*4 + reg  [m89/m91 verified]
  float bv[4];
  #pragma unroll
  for (int j = 0; j < 4; ++j)
    bv[j] = bias[(size_t)e * NDIM + nbase + wc * 64 + j * 16 + (lt & 15)];

  #pragma unroll
  for (int i = 0; i < 4; ++i) {
    int rowb = mbase + wr * 64 + i * 16 + (lt >> 4) * 4;
    #pragma unroll
    for (int r = 0; r < 4; ++r) {
      int row = rowb + r;
      if (G2) {
        int tok = rowmap[row];
        if (tok >= 0) {
          float* yp = yout + (size_t)tok * NDIM + nbase + wc * 64 + (lt & 15);
          #pragma unroll
          for (int j = 0; j < 4; ++j) yp[j * 16] = acc[i][j][r] + bv[j];
        }
      } else {
        u16* hp = hout + (size_t)row * NDIM + nbase + wc * 64 + (lt & 15);
        #pragma unroll
        for (int j = 0; j < 4; ++j) {
          float v = acc[i][j][r] + bv[j];
          v = 0.5f * v * (1.0f + erff(v * 0.70710678118654752f));   // exact gelu
          hp[j * 16] = f2bf(v);
        }
      }
    }
  }
}

extern "C" void kernel_launch(void* const* d_in, const int* in_sizes, int n_in,
                              void* d_out, int out_size, void* d_ws, size_t ws_size,
                              hipStream_t stream) {
  const float* x  = (const float*)d_in[0];
  const float* Wr = (const float*)d_in[1];
  const float* br = (const float*)d_in[2];
  const float* W1 = (const float*)d_in[3];
  const float* b1 = (const float*)d_in[4];
  const float* W2 = (const float*)d_in[5];
  const float* b2 = (const float*)d_in[6];
  float* out = (float*)d_out;

  char* ws = (char*)d_ws;
  int* eid    = (int*)(ws + 0);                 //   32768 B
  int* counts = (int*)(ws + 32768);             //   32 B
  int* fill   = (int*)(ws + 32768 + 64);        //   32 B
  int* poff   = (int*)(ws + 32768 + 128);       //   36 B
  int* rowmap = (int*)(ws + 33024);             //   36864 B
  u16* xbf    = (u16*)(ws + 69888);             //   16.78 MB
  u16* w1t    = (u16*)(ws + 16847104);          //   67.1 MB
  u16* w2t    = (u16*)(ws + 83955968);          //   67.1 MB
  u16* hbuf   = (u16*)(ws + 151064832);         //   75.5 MB  (total ~216 MiB)

  k_init<<<MAXROWS / 256, 256, 0, stream>>>(rowmap, counts, fill);
  k_route<<<TOK, 256, 0, stream>>>(x, Wr, br, eid, counts);
  k_scan<<<1, 64, 0, stream>>>(counts, poff);
  k_fillmap<<<TOK / 256, 256, 0, stream>>>(eid, poff, fill, rowmap);
  k_convx<<<(TOK * DD / 4) / 256, 256, 0, stream>>>(x, xbf);
  k_transpose<<<dim3(HH / 32, DD / 32, EE), 256, 0, stream>>>(W1, w1t, DD, HH);
  k_transpose<<<dim3(DD / 32, HH / 32, EE), 256, 0, stream>>>(W2, w2t, HH, DD);
  k_gemm<DD, HH, false><<<dim3(HH / 128, MAXMT), 256, 0, stream>>>(xbf, w1t, b1, poff, rowmap, hbuf, nullptr);
  k_gemm<HH, DD, true><<<dim3(DD / 128, MAXMT), 256, 0, stream>>>(hbuf, w2t, b2, poff, rowmap, nullptr, out);
}

// Round 2
// 723.480 us; speedup vs baseline: 1.0866x; 1.0866x over previous
//
#include <hip/hip_runtime.h>
#include <math.h>

#define TOK   8192
#define DD    1024
#define EE    8
#define HH    4096
#define MAXROWS 9216   // 8192 + 8*128 headroom, = 72 tiles * 128
#define MAXMT 72

typedef unsigned short u16;
typedef unsigned int   u32;
typedef __bf16 bf16x8 __attribute__((ext_vector_type(8)));
typedef float  f32x16 __attribute__((ext_vector_type(16)));

__device__ __forceinline__ u16 f2bf(float f) {
  union { float f; u32 u; } v; v.f = f;
  u32 r = v.u + 0x7fffu + ((v.u >> 16) & 1u);   // RNE, finite inputs only
  return (u16)(r >> 16);
}

__device__ __forceinline__ void gload16(const void* g, void* l) {
  __builtin_amdgcn_global_load_lds(
      (const __attribute__((address_space(1))) void*)g,
      (__attribute__((address_space(3))) void*)l, 16, 0, 0);
}

// ---------------- init: rowmap=-1, zero atomic counters ----------------
__global__ void k_init(int* rowmap, int* counts, int* fill) {
  int i = blockIdx.x * 256 + threadIdx.x;
  if (i < MAXROWS) rowmap[i] = -1;
  if (blockIdx.x == 0 && threadIdx.x < EE) { counts[threadIdx.x] = 0; fill[threadIdx.x] = 0; }
}

// ---------------- routing (1 wave/token) + fused x->bf16 conversion ----------------
__global__ __launch_bounds__(256)
void k_route(const float* __restrict__ x, const float* __restrict__ Wr,
             const float* __restrict__ br, int* __restrict__ eid,
             int* __restrict__ counts, u16* __restrict__ xb) {
  int t = blockIdx.x * 4 + (threadIdx.x >> 6);
  int lt = threadIdx.x & 63;
  const float4* xr = (const float4*)(x + (size_t)t * DD);
  u16* xbr = xb + (size_t)t * DD;
  const float4* wrp = (const float4*)Wr;
  float acc[EE];
  #pragma unroll
  for (int e = 0; e < EE; ++e) acc[e] = 0.f;
  #pragma unroll
  for (int i = 0; i < 4; ++i) {
    int d4 = lt + 64 * i;          // float4 index; d = 4*d4
    float4 v = xr[d4];
    u32 p0 = (u32)f2bf(v.x) | ((u32)f2bf(v.y) << 16);
    u32 p1 = (u32)f2bf(v.z) | ((u32)f2bf(v.w) << 16);
    ((uint2*)xbr)[d4] = make_uint2(p0, p1);
    float vv[4] = { v.x, v.y, v.z, v.w };
    #pragma unroll
    for (int dd = 0; dd < 4; ++dd) {
      float xv = vv[dd];
      float4 a = wrp[(size_t)(d4 * 4 + dd) * 2];
      float4 b = wrp[(size_t)(d4 * 4 + dd) * 2 + 1];
      acc[0] += xv * a.x; acc[1] += xv * a.y; acc[2] += xv * a.z; acc[3] += xv * a.w;
      acc[4] += xv * b.x; acc[5] += xv * b.y; acc[6] += xv * b.z; acc[7] += xv * b.w;
    }
  }
  #pragma unroll
  for (int e = 0; e < EE; ++e)
    #pragma unroll
    for (int off = 32; off > 0; off >>= 1) acc[e] += __shfl_down(acc[e], off);
  if (lt == 0) {
    float best = -1e30f; int be = 0;
    #pragma unroll
    for (int e = 0; e < EE; ++e) {
      float v = acc[e] + br[e];
      if (v > best) { best = v; be = e; }   // strict > = first index on tie (jnp.argmax)
    }
    eid[t] = be;
    atomicAdd(&counts[be], 1);
  }
}

// ---------------- scan: padded (x128) segment offsets ----------------
__global__ void k_scan(const int* __restrict__ counts, int* __restrict__ poff) {
  if (threadIdx.x == 0) {
    int off = 0; poff[0] = 0;
    for (int e = 0; e < EE; ++e) { off += ((counts[e] + 127) >> 7) << 7; poff[e + 1] = off; }
  }
}

// ---------------- fill rowmap: padded row -> token ----------------
__global__ void k_fillmap(const int* __restrict__ eid, const int* __restrict__ poff,
                          int* __restrict__ fill, int* __restrict__ rowmap) {
  int t = blockIdx.x * 256 + threadIdx.x;
  if (t < TOK) {
    int e = eid[t];
    int pos = atomicAdd(&fill[e], 1);
    rowmap[poff[e] + pos] = t;
  }
}

// ---------------- W [E][K][N] fp32 -> WT [E][N][K] bf16 (K-contiguous) ----------------
__global__ __launch_bounds__(256)
void k_transpose(const float* __restrict__ W, u16* __restrict__ WT, int K, int N) {
  __shared__ float tile[32][33];
  int e = blockIdx.z;
  int n0 = blockIdx.x * 32, k0 = blockIdx.y * 32;
  const float* We = W + (size_t)e * K * N;
  u16* WTe = WT + (size_t)e * K * N;
  int tx = threadIdx.x & 31, ty = threadIdx.x >> 5;
  #pragma unroll
  for (int i = 0; i < 4; ++i)
    tile[ty + 8 * i][tx] = We[(size_t)(k0 + ty + 8 * i) * N + n0 + tx];
  __syncthreads();
  #pragma unroll
  for (int i = 0; i < 4; ++i)
    WTe[(size_t)(n0 + ty + 8 * i) * K + k0 + tx] = f2bf(tile[tx][ty + 8 * i]);
}

// ---------------- 128x128 tile, 32x32x16 MFMA, BK=32, double-buffered LDS ----------------
// One barrier per K-iter: barrier -> issue next-buffer gloads -> compute current buffer.
// LDS chunk swizzle: phys_chunk = logical_chunk ^ (row & 3); chunks are 16 B (8 bf16).
// G2=false: C = gather(xbf) @ W1T[e]^T, epilogue bias+gelu -> h (bf16)
// G2=true : C = h @ W2T[e]^T, epilogue bias -> scatter fp32 rows to out
template <int KDIM, int NDIM, bool G2>
__global__ __launch_bounds__(256, 3)
void k_gemm(const u16* __restrict__ Abase, const u16* __restrict__ WT,
            const float* __restrict__ bias, const int* __restrict__ poff,
            const int* __restrict__ rowmap, u16* __restrict__ hout,
            float* __restrict__ yout) {
  const int mt = blockIdx.y;
  const int mbase = mt * 128;
  if (mbase >= poff[EE]) return;
  int e = 0;
  #pragma unroll
  for (int q = 1; q < EE; ++q) e += (mbase >= poff[q]) ? 1 : 0;

  const int nbase = blockIdx.x * 128;
  const int tid = threadIdx.x;
  const int w = tid >> 6;          // wave 0..3 in 2x2
  const int lt = tid & 63;
  const int wr = w >> 1, wc = w & 1;

  __shared__ u16 lsA[2][128 * 32];
  __shared__ u16 lsB[2][128 * 32];

  // ---- staging addresses: each wave fills 16 rows per gload16 (2 for A, 2 for B)
  const int srow = lt >> 2;                      // 0..15
  const int clog = (lt & 3) ^ (srow & 3);        // logical chunk for phys chunk lt&3
  int ar0, ar1;
  if (G2) { ar0 = mbase + w * 16 + srow; ar1 = ar0 + 64; }
  else {
    ar0 = rowmap[mbase + w * 16 + srow];      if (ar0 < 0) ar0 = 0;
    ar1 = rowmap[mbase + 64 + w * 16 + srow]; if (ar1 < 0) ar1 = 0;
  }
  const u16* gA0 = Abase + (size_t)ar0 * KDIM + clog * 8;
  const u16* gA1 = Abase + (size_t)ar1 * KDIM + clog * 8;
  const u16* wte = WT + (size_t)e * NDIM * KDIM + (size_t)nbase * KDIM;
  const u16* gB0 = wte + (size_t)(w * 16 + srow) * KDIM + clog * 8;
  const u16* gB1 = wte + (size_t)(64 + w * 16 + srow) * KDIM + clog * 8;

  f32x16 acc[2][2] = {};

  #define STAGE(buf, koff)                                          \
    do {                                                            \
      gload16(gA0 + (koff), &lsA[buf][(w * 16) * 32]);              \
      gload16(gA1 + (koff), &lsA[buf][(64 + w * 16) * 32]);         \
      gload16(gB0 + (koff), &lsB[buf][(w * 16) * 32]);              \
      gload16(gB1 + (koff), &lsB[buf][(64 + w * 16) * 32]);         \
    } while (0)

  STAGE(0, 0);
  const int KT = KDIM / 32;
  for (int bk = 0; bk < KT; ++bk) {
    __syncthreads();                 // drains prev-iter loads (issued a full compute phase ago)
    if (bk + 1 < KT) STAGE((bk + 1) & 1, (bk + 1) * 32);
    const u16* A = lsA[bk & 1];
    const u16* B = lsB[bk & 1];
    #pragma unroll
    for (int s = 0; s < 2; ++s) {
      bf16x8 af[2], bg[2];
      #pragma unroll
      for (int i = 0; i < 2; ++i) {
        int row = wr * 64 + i * 32 + (lt & 31);
        int phys = (s * 2 + (lt >> 5)) ^ (row & 3);
        af[i] = *(const bf16x8*)&A[row * 32 + phys * 8];
      }
      #pragma unroll
      for (int j = 0; j < 2; ++j) {
        int nn = wc * 64 + j * 32 + (lt & 31);
        int phys = (s * 2 + (lt >> 5)) ^ (nn & 3);
        bg[j] = *(const bf16x8*)&B[nn * 32 + phys * 8];
      }
      #pragma unroll
      for (int i = 0; i < 2; ++i)
        #pragma unroll
        for (int j = 0; j < 2; ++j)
          acc[i][j] = __builtin_amdgcn_mfma_f32_32x32x16_bf16(af[i], bg[j], acc[i][j], 0, 0, 0);
    }
  }
  #undef STAGE

  // ---- epilogue. 32x32 C/D layout: col = lane&31, row = (reg&3)+8*(reg>>2)+4*(lane>>5)  [m74/m101]
  float bv[2];
  #pragma unroll
  for (int j = 0; j < 2; ++j)
    bv[j] = bias[(size_t)e * NDIM + nbase + wc * 64 + j * 32 + (lt & 31)];

  #pragma unroll
  for (int i = 0; i < 2; ++i) {
    const int rbase = wr * 64 + i * 32 + 4 * (lt >> 5);
    #pragma unroll
    for (int r = 0; r < 16; ++r) {
      const int rl = rbase + (r & 3) + 8 * (r >> 2);
      const int grow = mbase + rl;
      if (G2) {
        int tok = rowmap[grow];
        if (tok >= 0) {
          float* yp = yout + (size_t)tok * NDIM + nbase + wc * 64 + (lt & 31);
          #pragma unroll
          for (int j = 0; j < 2; ++j) yp[j * 32] = acc[i][j][r] + bv[j];
        }
      } else {
        u16* hp = hout + (size_t)grow * NDIM + nbase + wc * 64 + (lt & 31);
        #pragma unroll
        for (int j = 0; j < 2; ++j) {
          float v = acc[i][j][r] + bv[j];
          v = 0.5f * v * (1.0f + erff(v * 0.70710678118654752f));   // exact gelu
          hp[j * 32] = f2bf(v);
        }
      }
    }
  }
}

extern "C" void kernel_launch(void* const* d_in, const int* in_sizes, int n_in,
                              void* d_out, int out_size, void* d_ws, size_t ws_size,
                              hipStream_t stream) {
  const float* x  = (const float*)d_in[0];
  const float* Wr = (const float*)d_in[1];
  const float* br = (const float*)d_in[2];
  const float* W1 = (const float*)d_in[3];
  const float* b1 = (const float*)d_in[4];
  const float* W2 = (const float*)d_in[5];
  const float* b2 = (const float*)d_in[6];
  float* out = (float*)d_out;

  char* ws = (char*)d_ws;
  int* eid    = (int*)(ws + 0);                 //   32768 B
  int* counts = (int*)(ws + 32768);             //   32 B
  int* fill   = (int*)(ws + 32768 + 64);        //   32 B
  int* poff   = (int*)(ws + 32768 + 128);       //   36 B
  int* rowmap = (int*)(ws + 33024);             //   36864 B
  u16* xbf    = (u16*)(ws + 69888);             //   16.78 MB
  u16* w1t    = (u16*)(ws + 16847104);          //   67.1 MB
  u16* w2t    = (u16*)(ws + 83955968);          //   67.1 MB
  u16* hbuf   = (u16*)(ws + 151064832);         //   75.5 MB  (total ~216 MiB)

  k_init<<<MAXROWS / 256, 256, 0, stream>>>(rowmap, counts, fill);
  k_route<<<TOK / 4, 256, 0, stream>>>(x, Wr, br, eid, counts, xbf);
  k_scan<<<1, 64, 0, stream>>>(counts, poff);
  k_fillmap<<<TOK / 256, 256, 0, stream>>>(eid, poff, fill, rowmap);
  k_transpose<<<dim3(HH / 32, DD / 32, EE), 256, 0, stream>>>(W1, w1t, DD, HH);
  k_transpose<<<dim3(DD / 32, HH / 32, EE), 256, 0, stream>>>(W2, w2t, HH, DD);
  k_gemm<DD, HH, false><<<dim3(HH / 128, MAXMT), 256, 0, stream>>>(xbf, w1t, b1, poff, rowmap, hbuf, nullptr);
  k_gemm<HH, DD, true><<<dim3(DD / 128, MAXMT), 256, 0, stream>>>(hbuf, w2t, b2, poff, rowmap, nullptr, out);
}